// Round 3
// baseline (65.238 us; speedup 1.0000x reference)
//
#include <hip/hip_runtime.h>

#define BATCH 1024
#define LEN   512
#define NTHREADS 256
#define MARGIN 1.0f

typedef float v2f __attribute__((ext_vector_type(2)));

// Kernel 1: one block per sample. Ballot-compact pos/neg into LDS,
// tile the (pos x neg) hinge sum, block-reduce, store ws[b].
//
// R5 changes vs R4 (63.3us):
//  - Pos register-blocking x2: inner loop computes 2 pos-chunks against the
//    same neg float4s. LDS broadcast reads + loop overhead halve per pair;
//    VALU stays at the 2.0 instr/pair floor (pk_add + 2x v_max + pk_acc per
//    2 pairs; CDNA4 has no v_pk_max_f32, so v_max is scalar).
//  - Odd-pchunk tail uses the single-chunk path (no dummy-q wasted pairs).
//  - Compaction flattened: both global load pairs issue before first ballot.
// No atomics to global: 1024-way same-address atomicAdd measured +7us (R2).
__global__ __launch_bounds__(NTHREADS) void per_sample_loss(
    const float* __restrict__ scores,   // [BATCH, LEN]
    const int*   __restrict__ labels,   // [BATCH, LEN], nonzero = positive
    float*       __restrict__ ws)       // [BATCH] per-sample loss
{
    __shared__ __align__(16) float pos[LEN];
    __shared__ __align__(16) float neg[LEN];
    __shared__ int cnt[2];              // [0]=n_pos, [1]=n_neg
    __shared__ float red[NTHREADS / 64];

    const int b    = blockIdx.x;
    const int tid  = threadIdx.x;
    const int lane = tid & 63;
    const int wave = tid >> 6;

    if (tid < 2) cnt[tid] = 0;
    __syncthreads();

    // ---- Compaction: wave ballot + prefix popcount, 2 LDS atomics/wave/seg.
    // Both loads issued up front to overlap HBM latency (inputs evicted from
    // L3 each iteration by the 268MB ws poison fill).
    const int base = b * LEN;
    const float s0 = scores[base + tid];
    const float s1 = scores[base + tid + NTHREADS];
    const int   la0 = labels[base + tid];
    const int   la1 = labels[base + tid + NTHREADS];
    const unsigned long long lt_mask = (1ull << lane) - 1ull;

    {
        const bool isp = (la0 != 0);
        const unsigned long long mp = __ballot(isp);
        const int np_wave = __popcll(mp);
        int basep = 0, basen = 0;
        if (lane == 0) {
            basep = atomicAdd(&cnt[0], np_wave);
            basen = atomicAdd(&cnt[1], 64 - np_wave);
        }
        basep = __shfl(basep, 0, 64);
        basen = __shfl(basen, 0, 64);
        if (isp) pos[basep + __popcll(mp  & lt_mask)] = s0;
        else     neg[basen + __popcll(~mp & lt_mask)] = s0;
    }
    {
        const bool isp = (la1 != 0);
        const unsigned long long mp = __ballot(isp);
        const int np_wave = __popcll(mp);
        int basep = 0, basen = 0;
        if (lane == 0) {
            basep = atomicAdd(&cnt[0], np_wave);
            basen = atomicAdd(&cnt[1], 64 - np_wave);
        }
        basep = __shfl(basep, 0, 64);
        basen = __shfl(basen, 0, 64);
        if (isp) pos[basep + __popcll(mp  & lt_mask)] = s1;
        else     neg[basen + __popcll(~mp & lt_mask)] = s1;
    }
    __syncthreads();

    const int n_pos = cnt[0];
    const int n_neg = cnt[1];

    // ---- Sentinel-pad: pos to mult-of-64 (lane dim), neg to mult-of-16
    // (inner-loop granularity, keeps float4 alignment).
    // pos sentinel +1e30 -> q = 1 - 1e30 hugely negative -> contributes 0.
    // neg sentinel -1e30 -> q + n hugely negative -> contributes 0.
    // (q+n worst case -2e30: finite in fp32, no inf/nan.)
    const int npos_pad = (n_pos + 63) & ~63;
    const int nneg_pad = (n_neg + 15) & ~15;
    for (int i = n_pos + tid; i < npos_pad; i += NTHREADS) pos[i] =  1e30f;
    for (int i = n_neg + tid; i < nneg_pad; i += NTHREADS) neg[i] = -1e30f;
    __syncthreads();

    // ---- Tiled pair loop, (2x64 pos lanes) x 16 neg tiles.
    // Wave w at pos-pair pp handles nc = ((w+pp)&3), +4, +8, ... -> every
    // (pp,nc) covered exactly once across 4 waves, balanced +-1, no runtime
    // division. Per 16-neg tile: 4 broadcast ds_read_b128 amortized over TWO
    // pos chunks (128 pairs/lane-pair): per 2 pairs {1 pk_add, 2 v_max,
    // 1 pk_add} = 2.0 instr/pair, LDS + loop overhead halved vs R4.
    const int pchunks = npos_pad >> 6;
    const int nchunks = nneg_pad >> 4;
    const int ppairs  = pchunks >> 1;
    const int podd    = pchunks & 1;

    v2f acc0 = {0.f, 0.f}, acc1 = {0.f, 0.f};
    v2f acc2 = {0.f, 0.f}, acc3 = {0.f, 0.f};
    const v2f zero = {0.f, 0.f};
    const float4* neg4 = reinterpret_cast<const float4*>(neg);

    for (int pp = 0; pp < ppairs; ++pp) {
        const int pc = pp << 1;
        const float qA = MARGIN - pos[(pc << 6) + lane];
        const float qB = MARGIN - pos[((pc + 1) << 6) + lane];
        const v2f qqA = {qA, qA};
        const v2f qqB = {qB, qB};

        for (int nc = (wave + pp) & 3; nc < nchunks; nc += 4) {
            const float4* nb = neg4 + (nc << 2);   // 16 floats = 4 float4
            #pragma unroll
            for (int j = 0; j < 4; j += 2) {
                const float4 n0 = nb[j];
                const float4 n1 = nb[j + 1];
                const v2f n0lo = {n0.x, n0.y}, n0hi = {n0.z, n0.w};
                const v2f n1lo = {n1.x, n1.y}, n1hi = {n1.z, n1.w};
                acc0 += __builtin_elementwise_max(qqA + n0lo, zero);
                acc1 += __builtin_elementwise_max(qqA + n0hi, zero);
                acc2 += __builtin_elementwise_max(qqA + n1lo, zero);
                acc3 += __builtin_elementwise_max(qqA + n1hi, zero);
                acc0 += __builtin_elementwise_max(qqB + n0lo, zero);
                acc1 += __builtin_elementwise_max(qqB + n0hi, zero);
                acc2 += __builtin_elementwise_max(qqB + n1lo, zero);
                acc3 += __builtin_elementwise_max(qqB + n1hi, zero);
            }
        }
    }
    if (podd) {
        const int pc = pchunks - 1;
        const float q = MARGIN - pos[(pc << 6) + lane];
        const v2f qq = {q, q};

        for (int nc = (wave + ppairs) & 3; nc < nchunks; nc += 4) {
            const float4* nb = neg4 + (nc << 2);
            #pragma unroll
            for (int j = 0; j < 4; j += 2) {
                const float4 n0 = nb[j];
                const float4 n1 = nb[j + 1];
                const v2f n0lo = {n0.x, n0.y}, n0hi = {n0.z, n0.w};
                const v2f n1lo = {n1.x, n1.y}, n1hi = {n1.z, n1.w};
                acc0 += __builtin_elementwise_max(qq + n0lo, zero);
                acc1 += __builtin_elementwise_max(qq + n0hi, zero);
                acc2 += __builtin_elementwise_max(qq + n1lo, zero);
                acc3 += __builtin_elementwise_max(qq + n1hi, zero);
            }
        }
    }

    const v2f accv = (acc0 + acc1) + (acc2 + acc3);
    float acc = accv.x + accv.y;

    // ---- Wave shuffle reduce, then across the 4 waves, single store.
    #pragma unroll
    for (int off = 32; off > 0; off >>= 1) acc += __shfl_down(acc, off, 64);
    if (lane == 0) red[wave] = acc;
    __syncthreads();

    if (tid == 0) {
        const float s = (red[0] + red[1]) + (red[2] + red[3]);
        const float n_pairs = (float)n_pos * (float)n_neg;
        ws[b] = s / fmaxf(n_pairs, 1.0f);
    }
}

// Kernel 2: deterministic reduction of BATCH per-sample losses -> mean.
// One float4 per thread (256 x 4 = 1024).
__global__ __launch_bounds__(NTHREADS) void reduce_batch(
    const float* __restrict__ ws, float* __restrict__ out)
{
    __shared__ float red[NTHREADS / 64];
    const int tid  = threadIdx.x;
    const int lane = tid & 63;
    const int wave = tid >> 6;

    const float4 v = reinterpret_cast<const float4*>(ws)[tid];
    float acc = (v.x + v.y) + (v.z + v.w);

    #pragma unroll
    for (int off = 32; off > 0; off >>= 1) acc += __shfl_down(acc, off, 64);
    if (lane == 0) red[wave] = acc;
    __syncthreads();

    if (tid == 0) {
        out[0] = ((red[0] + red[1]) + (red[2] + red[3])) * (1.0f / (float)BATCH);
    }
}

extern "C" void kernel_launch(void* const* d_in, const int* in_sizes, int n_in,
                              void* d_out, int out_size, void* d_ws, size_t ws_size,
                              hipStream_t stream) {
    const float* scores = (const float*)d_in[0];
    const int*   labels = (const int*)d_in[1];
    float*       out    = (float*)d_out;
    float*       ws     = (float*)d_ws;   // BATCH floats of scratch

    per_sample_loss<<<BATCH, NTHREADS, 0, stream>>>(scores, labels, ws);
    reduce_batch<<<1, NTHREADS, 0, stream>>>(ws, out);
}

// Round 4
// 65.184 us; speedup vs baseline: 1.0008x; 1.0008x over previous
//
#include <hip/hip_runtime.h>

#define BATCH 1024
#define LEN   512
#define NTHREADS 256
#define MARGIN 1.0f

typedef float v2f __attribute__((ext_vector_type(2)));

// Kernel 1: one block per sample. Ballot-compact pos/neg into LDS,
// tile the (pos x neg) hinge sum, block-reduce, store ws[b].
//
// R6 = exact revert to the R4 kernel (best measured: 63.3us).
// R5's pos-blocking x2 regressed +1.9us: halving the outer work-unit count
// (ppairs ~2 + odd tail) coarsened the staggered wave partition -> tail-wave
// imbalance cost exceeded the LDS-read savings. Reverted.
//
// Kernel structure (validated over R0-R4):
//  - Ballot-compact pos/neg into LDS (2 LDS atomics/wave/iter).
//  - Sentinel-pad pos to mult-64, neg to mult-16 -> branch-free tiles.
//  - Packed fp32 inner loop: per 2 pairs {v_pk_add_f32, 2x v_max_f32,
//    v_pk_add_f32} = 2.0 VALU instr/pair (CDNA4 has no v_pk_max_f32).
//  - Staggered (wave+pc)&3 partition: no runtime division, +-1 tile balance.
// No atomics to global: 1024-way same-address atomicAdd measured +7us (R2).
__global__ __launch_bounds__(NTHREADS) void per_sample_loss(
    const float* __restrict__ scores,   // [BATCH, LEN]
    const int*   __restrict__ labels,   // [BATCH, LEN], nonzero = positive
    float*       __restrict__ ws)       // [BATCH] per-sample loss
{
    __shared__ __align__(16) float pos[LEN];
    __shared__ __align__(16) float neg[LEN];
    __shared__ int cnt[2];              // [0]=n_pos, [1]=n_neg
    __shared__ float red[NTHREADS / 64];

    const int b    = blockIdx.x;
    const int tid  = threadIdx.x;
    const int lane = tid & 63;
    const int wave = tid >> 6;

    if (tid < 2) cnt[tid] = 0;
    __syncthreads();

    // ---- Compaction: wave ballot + prefix popcount, 2 LDS atomics/wave/iter.
    const unsigned long long lt_mask = (1ull << lane) - 1ull;
    #pragma unroll
    for (int iter = 0; iter < LEN / NTHREADS; ++iter) {
        const int l  = tid + iter * NTHREADS;
        const float s  = scores[b * LEN + l];
        const int   la = labels[b * LEN + l];
        const bool isp = (la != 0);

        const unsigned long long mp = __ballot(isp);
        const int np_wave = __popcll(mp);

        int basep = 0, basen = 0;
        if (lane == 0) {
            basep = atomicAdd(&cnt[0], np_wave);
            basen = atomicAdd(&cnt[1], 64 - np_wave);
        }
        basep = __shfl(basep, 0, 64);
        basen = __shfl(basen, 0, 64);

        if (isp) pos[basep + __popcll(mp  & lt_mask)] = s;
        else     neg[basen + __popcll(~mp & lt_mask)] = s;
    }
    __syncthreads();

    const int n_pos = cnt[0];
    const int n_neg = cnt[1];

    // ---- Sentinel-pad: pos to mult-of-64 (lane dim), neg to mult-of-16
    // (inner-loop granularity, keeps float4 alignment).
    // pos sentinel +1e30 -> q = 1 - 1e30 hugely negative -> contributes 0.
    // neg sentinel -1e30 -> q + n hugely negative -> contributes 0.
    // (q+n worst case -2e30: finite in fp32, no inf/nan.)
    const int npos_pad = (n_pos + 63) & ~63;
    const int nneg_pad = (n_neg + 15) & ~15;
    for (int i = n_pos + tid; i < npos_pad; i += NTHREADS) pos[i] =  1e30f;
    for (int i = n_neg + tid; i < nneg_pad; i += NTHREADS) neg[i] = -1e30f;
    __syncthreads();

    // ---- Tiled pair loop, 64(pos lanes) x 16(neg) tiles.
    // Wave w at pos-chunk pc handles nc = ((w+pc)&3), +4, +8, ... -> every
    // (pc,nc) covered exactly once across 4 waves, balanced +-1, no runtime
    // division. Per tile: 4 broadcast ds_read_b128 + packed-fp32 hinge.
    const int pchunks = npos_pad >> 6;
    const int nchunks = nneg_pad >> 4;

    v2f acc0 = {0.f, 0.f}, acc1 = {0.f, 0.f};
    v2f acc2 = {0.f, 0.f}, acc3 = {0.f, 0.f};
    const v2f zero = {0.f, 0.f};
    const float4* neg4 = reinterpret_cast<const float4*>(neg);

    for (int pc = 0; pc < pchunks; ++pc) {
        const float q = MARGIN - pos[(pc << 6) + lane];
        const v2f qq = {q, q};

        for (int nc = (wave + pc) & 3; nc < nchunks; nc += 4) {
            const float4* nb = neg4 + (nc << 2);   // 16 floats = 4 float4
            #pragma unroll
            for (int j = 0; j < 4; j += 2) {
                const float4 n0 = nb[j];
                const float4 n1 = nb[j + 1];
                const v2f n0lo = {n0.x, n0.y}, n0hi = {n0.z, n0.w};
                const v2f n1lo = {n1.x, n1.y}, n1hi = {n1.z, n1.w};
                acc0 += __builtin_elementwise_max(qq + n0lo, zero);
                acc1 += __builtin_elementwise_max(qq + n0hi, zero);
                acc2 += __builtin_elementwise_max(qq + n1lo, zero);
                acc3 += __builtin_elementwise_max(qq + n1hi, zero);
            }
        }
    }

    const v2f accv = (acc0 + acc1) + (acc2 + acc3);
    float acc = accv.x + accv.y;

    // ---- Wave shuffle reduce, then across the 4 waves, single store.
    #pragma unroll
    for (int off = 32; off > 0; off >>= 1) acc += __shfl_down(acc, off, 64);
    if (lane == 0) red[wave] = acc;
    __syncthreads();

    if (tid == 0) {
        const float s = (red[0] + red[1]) + (red[2] + red[3]);
        const float n_pairs = (float)n_pos * (float)n_neg;
        ws[b] = s / fmaxf(n_pairs, 1.0f);
    }
}

// Kernel 2: deterministic reduction of BATCH per-sample losses -> mean.
// One float4 per thread (256 x 4 = 1024).
__global__ __launch_bounds__(NTHREADS) void reduce_batch(
    const float* __restrict__ ws, float* __restrict__ out)
{
    __shared__ float red[NTHREADS / 64];
    const int tid  = threadIdx.x;
    const int lane = tid & 63;
    const int wave = tid >> 6;

    const float4 v = reinterpret_cast<const float4*>(ws)[tid];
    float acc = (v.x + v.y) + (v.z + v.w);

    #pragma unroll
    for (int off = 32; off > 0; off >>= 1) acc += __shfl_down(acc, off, 64);
    if (lane == 0) red[wave] = acc;
    __syncthreads();

    if (tid == 0) {
        out[0] = ((red[0] + red[1]) + (red[2] + red[3])) * (1.0f / (float)BATCH);
    }
}

extern "C" void kernel_launch(void* const* d_in, const int* in_sizes, int n_in,
                              void* d_out, int out_size, void* d_ws, size_t ws_size,
                              hipStream_t stream) {
    const float* scores = (const float*)d_in[0];
    const int*   labels = (const int*)d_in[1];
    float*       out    = (float*)d_out;
    float*       ws     = (float*)d_ws;   // BATCH floats of scratch

    per_sample_loss<<<BATCH, NTHREADS, 0, stream>>>(scores, labels, ws);
    reduce_batch<<<1, NTHREADS, 0, stream>>>(ws, out);
}